// Round 9
// baseline (298.526 us; speedup 1.0000x reference)
//
#include <hip/hip_runtime.h>

#define KS 23        // 736/32 K-steps for GEMM1

typedef short bfrag8 __attribute__((ext_vector_type(8)));
typedef float f32x4 __attribute__((ext_vector_type(4)));

__device__ __forceinline__ unsigned short f2bf(float f) {
  union { float f; unsigned u; } v; v.f = f;
  unsigned r = v.u + 0x7fffu + ((v.u >> 16) & 1u);
  return (unsigned short)(r >> 16);
}
__device__ __forceinline__ unsigned pk2(float a, float b) {
  return (unsigned)f2bf(a) | ((unsigned)f2bf(b) << 16);
}
__device__ __forceinline__ float bf2f(short s) {
  union { unsigned u; float f; } v;
  v.u = ((unsigned)(unsigned short)s) << 16;
  return v.f;
}

// ---- prep: weights -> fragment-major bf16 (contiguous 1KB per n16 x k32 MFMA tile) ----
__global__ void prep_weights(const float* __restrict__ cW1, const float* __restrict__ nW1,
                             const float* __restrict__ cW2, const float* __restrict__ nW2,
                             unsigned short* __restrict__ w1c, unsigned short* __restrict__ w1n,
                             unsigned short* __restrict__ w2c, unsigned short* __restrict__ w2n,
                             int* __restrict__ cnt) {
  int i = blockIdx.x * blockDim.x + threadIdx.x;
  if (i == 0) { cnt[0] = 0; cnt[1] = 0; }
  const int T0 = 12 * KS * 512, T1 = 8 * KS * 512, T2 = 8 * 6 * 512, T3 = 8 * 4 * 512;
  const int tot = T0 + T1 + T2 + T3;
  for (; i < tot; i += gridDim.x * blockDim.x) {
    int idx = i;
    const float* src; unsigned short* dst; int N, Kreal, KSm, rel;
    if (idx < T0)              { src = cW1; dst = w1c; N = 192; Kreal = 726; KSm = KS; rel = idx; }
    else if ((idx -= T0) < T1) { src = nW1; dst = w1n; N = 128; Kreal = 726; KSm = KS; rel = idx; }
    else if ((idx -= T1) < T2) { src = cW2; dst = w2c; N = 128; Kreal = 192; KSm = 6;  rel = idx; }
    else { idx -= T2;            src = nW2; dst = w2n; N = 128; Kreal = 128; KSm = 4;  rel = idx; }
    int blk = rel >> 9, within = rel & 511;
    int l = within >> 3, e = within & 7;
    int n16 = blk / KSm, k32 = blk - n16 * KSm;
    int n = n16 * 16 + (l & 15);
    int k = k32 * 32 + ((l >> 4) * 8) + e;
    dst[rel] = f2bf(k < Kreal ? src[(size_t)k * N + n] : 0.f);
  }
}

// ---- compaction: per-type packed records {src, dst, eid, packed_indices} ----
__global__ void compact_edges(const int* __restrict__ et,
                              const int* __restrict__ esrc, const int* __restrict__ edst,
                              const int* __restrict__ cts, const int* __restrict__ ctd,
                              const int* __restrict__ prs, const int* __restrict__ prd,
                              int* __restrict__ cnt, int4* __restrict__ r0, int4* __restrict__ r1,
                              float* __restrict__ out, int n) {
  int i = blockIdx.x * blockDim.x + threadIdx.x;
  for (; i < n; i += gridDim.x * blockDim.x) {
    int ty = et[i];
    if (ty == 0 || ty == 1) {
      int c1 = cts[i]; c1 = ((unsigned)c1 < 256u) ? c1 : 0;
      int c2 = ctd[i]; c2 = ((unsigned)c2 < 256u) ? c2 : 0;
      int p1 = prs[i]; p1 = ((unsigned)p1 < 64u)  ? p1 : 0;
      int p2 = prd[i]; p2 = ((unsigned)p2 < 64u)  ? p2 : 0;
      int4 rec; rec.x = esrc[i]; rec.y = edst[i]; rec.z = i;
      rec.w = c1 | (c2 << 8) | (p1 << 16) | (p2 << 22);
      if (ty == 0) r0[atomicAdd(&cnt[0], 1)] = rec;
      else         r1[atomicAdd(&cnt[1], 1)] = rec;
    } else {
      float4 z = make_float4(0.f, 0.f, 0.f, 0.f);
      float4* po = (float4*)(out + (size_t)i * 128);
      #pragma unroll
      for (int j = 0; j < 32; ++j) po[j] = z;
    }
  }
}

// load a node row's per-lane A-slice (4 runs of 8 floats at kq+32j) and pack to bf16 frags
__device__ __forceinline__ void loadrow(const float* __restrict__ p, int kq, bfrag8 f[4]) {
  #pragma unroll
  for (int j = 0; j < 4; ++j) {
    float4 x = *(const float4*)(p + j * 32 + kq);
    float4 y = *(const float4*)(p + j * 32 + kq + 4);
    union { bfrag8 b; uint4 q; } r;
    r.q = make_uint4(pk2(x.x, x.y), pk2(x.z, x.w), pk2(y.x, y.y), pk2(y.z, y.w));
    f[j] = r.b;
  }
}

// derived-segment A-fragment from bf16 u,v frags: op 0 = u*v, 1 = |u-v|, 2 = v-u
__device__ __forceinline__ bfrag8 dfrag(bfrag8 u, bfrag8 v, int op) {
  unsigned w[4];
  #pragma unroll
  for (int i = 0; i < 4; ++i) {
    float u0 = bf2f(u[2 * i]),     v0 = bf2f(v[2 * i]);
    float u1 = bf2f(u[2 * i + 1]), v1 = bf2f(v[2 * i + 1]);
    float x0 = (op == 0) ? u0 * v0 : (op == 1) ? fabsf(u0 - v0) : v0 - u0;
    float x1 = (op == 0) ? u1 * v1 : (op == 1) ? fabsf(u1 - v1) : v1 - u1;
    w[i] = pk2(x0, x1);
  }
  union { bfrag8 b; uint4 q; } r;
  r.q = make_uint4(w[0], w[1], w[2], w[3]);
  return r.b;
}

// ---- one wave processes 32 edges end-to-end; NO cross-wave sync anywhere ----
template <int CH>
__device__ __forceinline__ void mlp_wave(
    char* wls, int lane, int tile, int c, int etv,
    const int4* __restrict__ rec,
    const float* __restrict__ h_nodes, const float* __restrict__ edge_scalars,
    const float* __restrict__ emb_et, const float* __restrict__ emb_ct, const float* __restrict__ emb_pr,
    const unsigned short* __restrict__ w1f, const unsigned short* __restrict__ w2f,
    const float* __restrict__ b1, const float* __restrict__ g,
    const float* __restrict__ beta, const float* __restrict__ b2,
    float* __restrict__ out)
{
  constexpr int NF  = CH / 16;   // all-N fragments per wave (12 or 8)
  constexpr int KS2 = CH / 32;   // GEMM2 K-steps (6 or 4)
  constexpr int HST = CH + 8;    // hb row stride
  constexpr int EST = 104;       // emb row stride (96 + 8)
  unsigned short (*hb)[HST]  = (unsigned short (*)[HST])wls;   // written after emb reads done
  unsigned short (*emb)[EST] = (unsigned short (*)[EST])wls;   // overlay, used first

  const int lrow = lane & 15;
  const int grp  = lane >> 4;
  const int kq   = grp * 8;
  const int base = tile * 32;

  // records for this lane's two fragment rows
  int4 qa = rec[min(base + lrow, c - 1)];
  int4 qb = rec[min(base + 16 + lrow, c - 1)];

  // ---- emb gather: 2 lanes per row, wave-private LDS ----
  {
    const int rr = lane >> 1, hf = lane & 1;
    int4 qe = rec[min(base + rr, c - 1)];
    const int pk = qe.w;
    if (hf == 0) {
      const float* tps[3] = { emb_et + etv * 16,
                              emb_ct + (pk & 255) * 16,
                              emb_ct + ((pk >> 8) & 255) * 16 };
      #pragma unroll
      for (int tb = 0; tb < 3; ++tb) {
        const float4* tp = (const float4*)tps[tb];
        float4 a = tp[0], b4 = tp[1], c4 = tp[2], d4 = tp[3];
        *(uint4*)&emb[rr][tb * 16 + 0] =
          make_uint4(pk2(a.x, a.y), pk2(a.z, a.w), pk2(b4.x, b4.y), pk2(b4.z, b4.w));
        *(uint4*)&emb[rr][tb * 16 + 8] =
          make_uint4(pk2(c4.x, c4.y), pk2(c4.z, c4.w), pk2(d4.x, d4.y), pk2(d4.z, d4.w));
      }
    } else {
      const float* tps[2] = { emb_pr + ((pk >> 16) & 63) * 16,
                              emb_pr + ((pk >> 22) & 63) * 16 };
      #pragma unroll
      for (int tb = 0; tb < 2; ++tb) {
        const float4* tp = (const float4*)tps[tb];
        float4 a = tp[0], b4 = tp[1], c4 = tp[2], d4 = tp[3];
        *(uint4*)&emb[rr][48 + tb * 16 + 0] =
          make_uint4(pk2(a.x, a.y), pk2(a.z, a.w), pk2(b4.x, b4.y), pk2(b4.z, b4.w));
        *(uint4*)&emb[rr][48 + tb * 16 + 8] =
          make_uint4(pk2(c4.x, c4.y), pk2(c4.z, c4.w), pk2(d4.x, d4.y), pk2(d4.z, d4.w));
      }
      const float2* sp = (const float2*)(edge_scalars + (size_t)qe.z * 6);
      float2 s0 = sp[0], s1 = sp[1], s2 = sp[2];
      float v0 = fminf(fmaxf(s0.x, -10.f), 10.f), v1 = fminf(fmaxf(s0.y, -10.f), 10.f);
      float v2 = fminf(fmaxf(s1.x, -10.f), 10.f), v3 = fminf(fmaxf(s1.y, -10.f), 10.f);
      float v4 = fminf(fmaxf(s2.x, -10.f), 10.f), v5 = fminf(fmaxf(s2.y, -10.f), 10.f);
      *(uint4*)&emb[rr][80] = make_uint4(pk2(v0, v1), pk2(v2, v3), pk2(v4, v5), 0u);
      *(uint4*)&emb[rr][88] = make_uint4(0u, 0u, 0u, 0u);
    }
  }

  // ---- u,v A-fragments straight into registers (bf16) ----
  bfrag8 ua[4], va[4], ub[4], vb[4];
  loadrow(h_nodes + (size_t)qa.x * 128, kq, ua);
  loadrow(h_nodes + (size_t)qa.y * 128, kq, va);
  loadrow(h_nodes + (size_t)qb.x * 128, kq, ub);
  loadrow(h_nodes + (size_t)qb.y * 128, kq, vb);

  // ---- GEMM1: 20 reg-sourced K-steps + 3 emb K-steps; A-frags in regs ----
  f32x4 acc1[2][NF];
  #pragma unroll
  for (int mf = 0; mf < 2; ++mf)
    #pragma unroll
    for (int nf = 0; nf < NF; ++nf) acc1[mf][nf] = 0;
  const unsigned short* wbl = w1f + (size_t)lane * 8;

  #pragma unroll
  for (int seg = 0; seg < 5; ++seg) {
    #pragma unroll
    for (int k = 0; k < 4; ++k) {
      const int kk = seg * 4 + k;
      bfrag8 a0, a1;
      if (seg == 0)      { a0 = ua[k]; a1 = ub[k]; }
      else if (seg == 1) { a0 = va[k]; a1 = vb[k]; }
      else { a0 = dfrag(ua[k], va[k], seg - 2); a1 = dfrag(ub[k], vb[k], seg - 2); }
      #pragma unroll
      for (int nf = 0; nf < NF; ++nf) {
        bfrag8 bf = *(const bfrag8*)(wbl + ((size_t)(nf * KS + kk)) * 512);
        acc1[0][nf] = __builtin_amdgcn_mfma_f32_16x16x32_bf16(a0, bf, acc1[0][nf], 0, 0, 0);
        acc1[1][nf] = __builtin_amdgcn_mfma_f32_16x16x32_bf16(a1, bf, acc1[1][nf], 0, 0, 0);
      }
    }
  }
  #pragma unroll
  for (int k = 0; k < 3; ++k) {
    const int kk = 20 + k;
    bfrag8 a0 = *(const bfrag8*)&emb[lrow][k * 32 + kq];
    bfrag8 a1 = *(const bfrag8*)&emb[16 + lrow][k * 32 + kq];
    #pragma unroll
    for (int nf = 0; nf < NF; ++nf) {
      bfrag8 bf = *(const bfrag8*)(wbl + ((size_t)(nf * KS + kk)) * 512);
      acc1[0][nf] = __builtin_amdgcn_mfma_f32_16x16x32_bf16(a0, bf, acc1[0][nf], 0, 0, 0);
      acc1[1][nf] = __builtin_amdgcn_mfma_f32_16x16x32_bf16(a1, bf, acc1[1][nf], 0, 0, 0);
    }
  }

  // ---- LN params (loaded late to keep GEMM1 register pressure down) ----
  float b1r[NF], gr[NF], ber[NF];
  #pragma unroll
  for (int nf = 0; nf < NF; ++nf) {
    int n = nf * 16 + lrow;
    b1r[nf] = b1[n]; gr[nf] = g[n]; ber[nf] = beta[n];
  }

  // ---- LayerNorm fully in-register: 16-lane group holds full rows ----
  float sums[2][4], sqs[2][4];
  #pragma unroll
  for (int mf = 0; mf < 2; ++mf)
    #pragma unroll
    for (int rg = 0; rg < 4; ++rg) {
      float s = 0.f, qd = 0.f;
      #pragma unroll
      for (int nf = 0; nf < NF; ++nf) {
        float v = acc1[mf][nf][rg] + b1r[nf];
        acc1[mf][nf][rg] = v;
        s += v; qd += v * v;
      }
      sums[mf][rg] = s; sqs[mf][rg] = qd;
    }
  #pragma unroll
  for (int d = 1; d < 16; d <<= 1) {
    #pragma unroll
    for (int mf = 0; mf < 2; ++mf)
      #pragma unroll
      for (int rg = 0; rg < 4; ++rg) {
        sums[mf][rg] += __shfl_xor(sums[mf][rg], d);
        sqs[mf][rg]  += __shfl_xor(sqs[mf][rg], d);
      }
  }
  // normalize + relu -> hb (wave-private; overwrites emb region only after emb reads)
  #pragma unroll
  for (int mf = 0; mf < 2; ++mf)
    #pragma unroll
    for (int rg = 0; rg < 4; ++rg) {
      float mu = sums[mf][rg] * (1.f / CH);
      float var = fmaxf(sqs[mf][rg] * (1.f / CH) - mu * mu, 0.f);
      float rs = rsqrtf(var + 1e-5f);
      int row = mf * 16 + grp * 4 + rg;
      #pragma unroll
      for (int nf = 0; nf < NF; ++nf) {
        float v = (acc1[mf][nf][rg] - mu) * rs * gr[nf] + ber[nf];
        hb[row][nf * 16 + lrow] = f2bf(fmaxf(v, 0.f));
      }
    }

  // ---- GEMM2: all 128 out-cols per wave ----
  float b2r[8];
  #pragma unroll
  for (int nf2 = 0; nf2 < 8; ++nf2) b2r[nf2] = b2[nf2 * 16 + lrow];

  f32x4 acc2[2][8];
  #pragma unroll
  for (int mf = 0; mf < 2; ++mf)
    #pragma unroll
    for (int nf2 = 0; nf2 < 8; ++nf2) acc2[mf][nf2] = 0;
  const unsigned short* wbl2 = w2f + (size_t)lane * 8;
  #pragma unroll
  for (int k2 = 0; k2 < KS2; ++k2) {
    bfrag8 a0 = *(const bfrag8*)&hb[lrow][k2 * 32 + kq];
    bfrag8 a1 = *(const bfrag8*)&hb[16 + lrow][k2 * 32 + kq];
    #pragma unroll
    for (int nf2 = 0; nf2 < 8; ++nf2) {
      bfrag8 bf = *(const bfrag8*)(wbl2 + ((size_t)(nf2 * KS2 + k2)) * 512);
      acc2[0][nf2] = __builtin_amdgcn_mfma_f32_16x16x32_bf16(a0, bf, acc2[0][nf2], 0, 0, 0);
      acc2[1][nf2] = __builtin_amdgcn_mfma_f32_16x16x32_bf16(a1, bf, acc2[1][nf2], 0, 0, 0);
    }
  }

  // ---- stores: eid fetched by wave shuffle from record-holding lanes ----
  #pragma unroll
  for (int mf = 0; mf < 2; ++mf)
    #pragma unroll
    for (int rg = 0; rg < 4; ++rg) {
      const int rowLow = grp * 4 + rg;
      const int eid = __shfl(mf ? qb.z : qa.z, rowLow);
      if (base + mf * 16 + rowLow < c) {
        float* po = out + (size_t)eid * 128 + lrow;
        #pragma unroll
        for (int nf2 = 0; nf2 < 8; ++nf2)
          po[nf2 * 16] = acc2[mf][nf2][rg] + b2r[nf2];
      }
    }
}

struct Args {
  const float *h_nodes, *edge_scalars;
  const float *emb_et, *emb_ct, *emb_pr;
  const unsigned short *w1c, *w2c;
  const float *cb1, *cg, *cbe, *cb2;
  const unsigned short *w1n, *w2n;
  const float *nb1, *ng, *nbe, *nb2;
  const int *cnt;
  const int4 *r0, *r1;
  float* out;
};

__global__ __launch_bounds__(256, 2) void edge_mlp_all(Args A) {
  __shared__ alignas(16) char smraw[4 * 12800];
  const int wid = threadIdx.x >> 6;
  const int lane = threadIdx.x & 63;
  char* wls = smraw + wid * 12800;
  const int w = blockIdx.x * 4 + wid;
  const int c0 = A.cnt[0];
  const int t0 = (c0 + 31) >> 5;
  if (w < t0) {
    mlp_wave<192>(wls, lane, w, c0, 0, A.r0, A.h_nodes, A.edge_scalars,
                  A.emb_et, A.emb_ct, A.emb_pr, A.w1c, A.w2c,
                  A.cb1, A.cg, A.cbe, A.cb2, A.out);
  } else {
    const int c1 = A.cnt[1];
    const int w1 = w - t0;
    if (w1 * 32 < c1)
      mlp_wave<128>(wls, lane, w1, c1, 1, A.r1, A.h_nodes, A.edge_scalars,
                    A.emb_et, A.emb_ct, A.emb_pr, A.w1n, A.w2n,
                    A.nb1, A.ng, A.nbe, A.nb2, A.out);
  }
}

extern "C" void kernel_launch(void* const* d_in, const int* in_sizes, int n_in,
                              void* d_out, int out_size, void* d_ws, size_t ws_size,
                              hipStream_t stream) {
  (void)n_in; (void)out_size; (void)ws_size;
  const float* h_nodes      = (const float*)d_in[0];
  const float* edge_scalars = (const float*)d_in[1];
  const int*   edge_src     = (const int*)d_in[2];
  const int*   edge_dst     = (const int*)d_in[3];
  const int*   edge_type    = (const int*)d_in[4];
  const int*   ct_s         = (const int*)d_in[5];
  const int*   ct_d         = (const int*)d_in[6];
  const int*   pr_s         = (const int*)d_in[7];
  const int*   pr_d         = (const int*)d_in[8];
  const float* emb_et       = (const float*)d_in[9];
  const float* emb_ct       = (const float*)d_in[10];
  const float* emb_pr       = (const float*)d_in[11];
  const float* cW1 = (const float*)d_in[12];
  const float* cb1 = (const float*)d_in[13];
  const float* cg  = (const float*)d_in[14];
  const float* cbe = (const float*)d_in[15];
  const float* cW2 = (const float*)d_in[16];
  const float* cb2 = (const float*)d_in[17];
  const float* nW1 = (const float*)d_in[18];
  const float* nb1 = (const float*)d_in[19];
  const float* ng  = (const float*)d_in[20];
  const float* nbe = (const float*)d_in[21];
  const float* nW2 = (const float*)d_in[22];
  const float* nb2 = (const float*)d_in[23];
  const int n_edges = in_sizes[2];
  float* out = (float*)d_out;

  char* ws = (char*)d_ws;
  int* cnt = (int*)ws;
  int4* r0 = (int4*)(ws + 256);
  int4* r1 = r0 + n_edges;
  size_t woff = (256 + (size_t)2 * n_edges * sizeof(int4) + 255) & ~(size_t)255;
  unsigned short* w1c = (unsigned short*)(ws + woff);
  unsigned short* w1n = w1c + 12 * KS * 512;
  unsigned short* w2c = w1n + 8 * KS * 512;
  unsigned short* w2n = w2c + 8 * 6 * 512;

  prep_weights<<<1080, 256, 0, stream>>>(cW1, nW1, cW2, nW2, w1c, w1n, w2c, w2n, cnt);
  compact_edges<<<(n_edges + 255) / 256, 256, 0, stream>>>(edge_type, edge_src, edge_dst,
                                                           ct_s, ct_d, pr_s, pr_d,
                                                           cnt, r0, r1, out, n_edges);

  Args A;
  A.h_nodes = h_nodes; A.edge_scalars = edge_scalars;
  A.emb_et = emb_et; A.emb_ct = emb_ct; A.emb_pr = emb_pr;
  A.w1c = w1c; A.w2c = w2c; A.cb1 = cb1; A.cg = cg; A.cbe = cbe; A.cb2 = cb2;
  A.w1n = w1n; A.w2n = w2n; A.nb1 = nb1; A.ng = ng; A.nbe = nbe; A.nb2 = nb2;
  A.cnt = cnt; A.r0 = r0; A.r1 = r1; A.out = out;

  const int waves = (n_edges + 31) / 32 + 2;
  const int nbAll = (waves + 3) / 4;
  edge_mlp_all<<<nbAll, 256, 0, stream>>>(A);
}

// Round 10
// 259.518 us; speedup vs baseline: 1.1503x; 1.1503x over previous
//
#include <hip/hip_runtime.h>

#define KS 23        // 736/32 K-steps for GEMM1

typedef short bfrag8 __attribute__((ext_vector_type(8)));
typedef float f32x4 __attribute__((ext_vector_type(4)));

__device__ __forceinline__ unsigned short f2bf(float f) {
  union { float f; unsigned u; } v; v.f = f;
  unsigned r = v.u + 0x7fffu + ((v.u >> 16) & 1u);
  return (unsigned short)(r >> 16);
}
__device__ __forceinline__ unsigned pk2(float a, float b) {
  return (unsigned)f2bf(a) | ((unsigned)f2bf(b) << 16);
}
__device__ __forceinline__ float bf2f(short s) {
  union { unsigned u; float f; } v;
  v.u = ((unsigned)(unsigned short)s) << 16;
  return v.f;
}

// ---- prep: weights -> fragment-major bf16 (contiguous 1KB per n16 x k32 MFMA tile) ----
__global__ void prep_weights(const float* __restrict__ cW1, const float* __restrict__ nW1,
                             const float* __restrict__ cW2, const float* __restrict__ nW2,
                             unsigned short* __restrict__ w1c, unsigned short* __restrict__ w1n,
                             unsigned short* __restrict__ w2c, unsigned short* __restrict__ w2n,
                             int* __restrict__ cnt) {
  int i = blockIdx.x * blockDim.x + threadIdx.x;
  if (i == 0) { cnt[0] = 0; cnt[1] = 0; }
  const int T0 = 12 * KS * 512, T1 = 8 * KS * 512, T2 = 8 * 6 * 512, T3 = 8 * 4 * 512;
  const int tot = T0 + T1 + T2 + T3;
  for (; i < tot; i += gridDim.x * blockDim.x) {
    int idx = i;
    const float* src; unsigned short* dst; int N, Kreal, KSm, rel;
    if (idx < T0)              { src = cW1; dst = w1c; N = 192; Kreal = 726; KSm = KS; rel = idx; }
    else if ((idx -= T0) < T1) { src = nW1; dst = w1n; N = 128; Kreal = 726; KSm = KS; rel = idx; }
    else if ((idx -= T1) < T2) { src = cW2; dst = w2c; N = 128; Kreal = 192; KSm = 6;  rel = idx; }
    else { idx -= T2;            src = nW2; dst = w2n; N = 128; Kreal = 128; KSm = 4;  rel = idx; }
    int blk = rel >> 9, within = rel & 511;
    int l = within >> 3, e = within & 7;
    int n16 = blk / KSm, k32 = blk - n16 * KSm;
    int n = n16 * 16 + (l & 15);
    int k = k32 * 32 + ((l >> 4) * 8) + e;
    dst[rel] = f2bf(k < Kreal ? src[(size_t)k * N + n] : 0.f);
  }
}

// ---- compaction: per-type packed records {src, dst, eid, packed_indices} ----
__global__ void compact_edges(const int* __restrict__ et,
                              const int* __restrict__ esrc, const int* __restrict__ edst,
                              const int* __restrict__ cts, const int* __restrict__ ctd,
                              const int* __restrict__ prs, const int* __restrict__ prd,
                              int* __restrict__ cnt, int4* __restrict__ r0, int4* __restrict__ r1,
                              float* __restrict__ out, int n) {
  int i = blockIdx.x * blockDim.x + threadIdx.x;
  for (; i < n; i += gridDim.x * blockDim.x) {
    int ty = et[i];
    if (ty == 0 || ty == 1) {
      int c1 = cts[i]; c1 = ((unsigned)c1 < 256u) ? c1 : 0;
      int c2 = ctd[i]; c2 = ((unsigned)c2 < 256u) ? c2 : 0;
      int p1 = prs[i]; p1 = ((unsigned)p1 < 64u)  ? p1 : 0;
      int p2 = prd[i]; p2 = ((unsigned)p2 < 64u)  ? p2 : 0;
      int4 rec; rec.x = esrc[i]; rec.y = edst[i]; rec.z = i;
      rec.w = c1 | (c2 << 8) | (p1 << 16) | (p2 << 22);
      if (ty == 0) r0[atomicAdd(&cnt[0], 1)] = rec;
      else         r1[atomicAdd(&cnt[1], 1)] = rec;
    } else {
      float4 z = make_float4(0.f, 0.f, 0.f, 0.f);
      float4* po = (float4*)(out + (size_t)i * 128);
      #pragma unroll
      for (int j = 0; j < 32; ++j) po[j] = z;
    }
  }
}

// load a node row's per-lane A-slice (4 runs of 8 floats at kq+32j) packed to bf16 frags
__device__ __forceinline__ void loadrow(const float* __restrict__ p, int kq, bfrag8 f[4]) {
  #pragma unroll
  for (int j = 0; j < 4; ++j) {
    float4 x = *(const float4*)(p + j * 32 + kq);
    float4 y = *(const float4*)(p + j * 32 + kq + 4);
    union { bfrag8 b; uint4 q; } r;
    r.q = make_uint4(pk2(x.x, x.y), pk2(x.z, x.w), pk2(y.x, y.y), pk2(y.z, y.w));
    f[j] = r.b;
  }
}

// derived-segment A-fragment: op 0 = u*v, 1 = |u-v|, 2 = v-u
__device__ __forceinline__ bfrag8 dfrag(bfrag8 u, bfrag8 v, int op) {
  unsigned w[4];
  #pragma unroll
  for (int i = 0; i < 4; ++i) {
    float u0 = bf2f(u[2 * i]),     v0 = bf2f(v[2 * i]);
    float u1 = bf2f(u[2 * i + 1]), v1 = bf2f(v[2 * i + 1]);
    float x0 = (op == 0) ? u0 * v0 : (op == 1) ? fabsf(u0 - v0) : v0 - u0;
    float x1 = (op == 0) ? u1 * v1 : (op == 1) ? fabsf(u1 - v1) : v1 - u1;
    w[i] = pk2(x0, x1);
  }
  union { bfrag8 b; uint4 q; } r;
  r.q = make_uint4(w[0], w[1], w[2], w[3]);
  return r.b;
}

// ---- 2 waves cooperate on 32 edges; wave ni owns N-half. 2 barriers total. ----
template <int CH>
__device__ __forceinline__ void mlp_tile2(
    char* smraw, int lane, int ni, int tile, int c, int etv,
    const int4* __restrict__ rec,
    const float* __restrict__ h_nodes, const float* __restrict__ edge_scalars,
    const float* __restrict__ emb_et, const float* __restrict__ emb_ct, const float* __restrict__ emb_pr,
    const unsigned short* __restrict__ w1f, const unsigned short* __restrict__ w2f,
    const float* __restrict__ b1, const float* __restrict__ g,
    const float* __restrict__ beta, const float* __restrict__ b2,
    float* __restrict__ out)
{
  constexpr int NF  = CH / 32;   // GEMM1 n-frags per wave (6 or 4)
  constexpr int KS2 = CH / 32;   // GEMM2 K-steps (6 or 4)
  constexpr int HST = CH + 8;    // hb row stride
  constexpr int EST = 104;       // emb row stride
  unsigned short (*emb)[EST] = (unsigned short (*)[EST])(smraw + ni * 6656);  // wave-private
  unsigned short (*hb)[HST]  = (unsigned short (*)[HST])smraw;                // overlays emb post-barrier1
  float (*red)[32][2] = (float (*)[32][2])(smraw + 13312);

  const int lrow = lane & 15;
  const int grp  = lane >> 4;
  const int kq   = grp * 8;
  const int base = tile * 32;

  int4 qa = rec[min(base + lrow, c - 1)];
  int4 qb = rec[min(base + 16 + lrow, c - 1)];

  // ---- emb gather into wave-private LDS (2 lanes per row) ----
  {
    const int rr = lane >> 1, hf = lane & 1;
    int4 qe = rec[min(base + rr, c - 1)];
    const int pk = qe.w;
    if (hf == 0) {
      const float* tps[3] = { emb_et + etv * 16,
                              emb_ct + (pk & 255) * 16,
                              emb_ct + ((pk >> 8) & 255) * 16 };
      #pragma unroll
      for (int tb = 0; tb < 3; ++tb) {
        const float4* tp = (const float4*)tps[tb];
        float4 a = tp[0], b4 = tp[1], c4 = tp[2], d4 = tp[3];
        *(uint4*)&emb[rr][tb * 16 + 0] =
          make_uint4(pk2(a.x, a.y), pk2(a.z, a.w), pk2(b4.x, b4.y), pk2(b4.z, b4.w));
        *(uint4*)&emb[rr][tb * 16 + 8] =
          make_uint4(pk2(c4.x, c4.y), pk2(c4.z, c4.w), pk2(d4.x, d4.y), pk2(d4.z, d4.w));
      }
    } else {
      const float* tps[2] = { emb_pr + ((pk >> 16) & 63) * 16,
                              emb_pr + ((pk >> 22) & 63) * 16 };
      #pragma unroll
      for (int tb = 0; tb < 2; ++tb) {
        const float4* tp = (const float4*)tps[tb];
        float4 a = tp[0], b4 = tp[1], c4 = tp[2], d4 = tp[3];
        *(uint4*)&emb[rr][48 + tb * 16 + 0] =
          make_uint4(pk2(a.x, a.y), pk2(a.z, a.w), pk2(b4.x, b4.y), pk2(b4.z, b4.w));
        *(uint4*)&emb[rr][48 + tb * 16 + 8] =
          make_uint4(pk2(c4.x, c4.y), pk2(c4.z, c4.w), pk2(d4.x, d4.y), pk2(d4.z, d4.w));
      }
      const float2* sp = (const float2*)(edge_scalars + (size_t)qe.z * 6);
      float2 s0 = sp[0], s1 = sp[1], s2 = sp[2];
      float v0 = fminf(fmaxf(s0.x, -10.f), 10.f), v1 = fminf(fmaxf(s0.y, -10.f), 10.f);
      float v2 = fminf(fmaxf(s1.x, -10.f), 10.f), v3 = fminf(fmaxf(s1.y, -10.f), 10.f);
      float v4 = fminf(fmaxf(s2.x, -10.f), 10.f), v5 = fminf(fmaxf(s2.y, -10.f), 10.f);
      *(uint4*)&emb[rr][80] = make_uint4(pk2(v0, v1), pk2(v2, v3), pk2(v4, v5), 0u);
      *(uint4*)&emb[rr][88] = make_uint4(0u, 0u, 0u, 0u);
    }
  }

  // ---- u,v A-fragments straight into registers ----
  bfrag8 ua[4], va[4], ub[4], vb[4];
  loadrow(h_nodes + (size_t)qa.x * 128, kq, ua);
  loadrow(h_nodes + (size_t)qa.y * 128, kq, va);
  loadrow(h_nodes + (size_t)qb.x * 128, kq, ub);
  loadrow(h_nodes + (size_t)qb.y * 128, kq, vb);

  // ---- GEMM1: flat 23 K-steps, depth-1 B ring; A from regs (emb for kk>=20) ----
  f32x4 acc1[2][NF];
  #pragma unroll
  for (int mf = 0; mf < 2; ++mf)
    #pragma unroll
    for (int nf = 0; nf < NF; ++nf) acc1[mf][nf] = 0;
  const unsigned short* wbl = w1f + ((size_t)ni * NF * KS) * 512 + (size_t)lane * 8;

  bfrag8 br[2][NF];
  #pragma unroll
  for (int nf = 0; nf < NF; ++nf)
    br[0][nf] = *(const bfrag8*)(wbl + ((size_t)nf * KS) * 512);
  #pragma unroll
  for (int kk = 0; kk < 23; ++kk) {
    if (kk + 1 < 23) {
      #pragma unroll
      for (int nf = 0; nf < NF; ++nf)
        br[(kk + 1) & 1][nf] = *(const bfrag8*)(wbl + ((size_t)nf * KS + kk + 1) * 512);
    }
    bfrag8 a0, a1;
    const int seg = kk >> 2, k = kk & 3;
    if (kk >= 20) {
      a0 = *(const bfrag8*)&emb[lrow][(kk - 20) * 32 + kq];
      a1 = *(const bfrag8*)&emb[16 + lrow][(kk - 20) * 32 + kq];
    } else if (seg == 0) { a0 = ua[k]; a1 = ub[k]; }
    else if (seg == 1)   { a0 = va[k]; a1 = vb[k]; }
    else { a0 = dfrag(ua[k], va[k], seg - 2); a1 = dfrag(ub[k], vb[k], seg - 2); }
    #pragma unroll
    for (int nf = 0; nf < NF; ++nf) {
      acc1[0][nf] = __builtin_amdgcn_mfma_f32_16x16x32_bf16(a0, br[kk & 1][nf], acc1[0][nf], 0, 0, 0);
      acc1[1][nf] = __builtin_amdgcn_mfma_f32_16x16x32_bf16(a1, br[kk & 1][nf], acc1[1][nf], 0, 0, 0);
    }
  }

  // ---- bias fold + partial LN sums over this wave's half ----
  float b1r[NF], gr[NF], ber[NF];
  #pragma unroll
  for (int nf = 0; nf < NF; ++nf) {
    int n = ni * (CH / 2) + nf * 16 + lrow;
    b1r[nf] = b1[n]; gr[nf] = g[n]; ber[nf] = beta[n];
  }
  float sums[2][4], sqs[2][4];
  #pragma unroll
  for (int mf = 0; mf < 2; ++mf)
    #pragma unroll
    for (int rg = 0; rg < 4; ++rg) {
      float s = 0.f, qd = 0.f;
      #pragma unroll
      for (int nf = 0; nf < NF; ++nf) {
        float v = acc1[mf][nf][rg] + b1r[nf];
        acc1[mf][nf][rg] = v;
        s += v; qd += v * v;
      }
      sums[mf][rg] = s; sqs[mf][rg] = qd;
    }
  #pragma unroll
  for (int d = 1; d < 16; d <<= 1) {
    #pragma unroll
    for (int mf = 0; mf < 2; ++mf)
      #pragma unroll
      for (int rg = 0; rg < 4; ++rg) {
        sums[mf][rg] += __shfl_xor(sums[mf][rg], d);
        sqs[mf][rg]  += __shfl_xor(sqs[mf][rg], d);
      }
  }
  if (lrow == 0) {
    #pragma unroll
    for (int mf = 0; mf < 2; ++mf)
      #pragma unroll
      for (int rg = 0; rg < 4; ++rg) {
        int row = mf * 16 + grp * 4 + rg;
        red[ni][row][0] = sums[mf][rg];
        red[ni][row][1] = sqs[mf][rg];
      }
  }
  __syncthreads();   // barrier 1: partials ready (emb reads complete -> hb overlay safe)

  // ---- normalize + relu -> hb (block-shared) ----
  #pragma unroll
  for (int mf = 0; mf < 2; ++mf)
    #pragma unroll
    for (int rg = 0; rg < 4; ++rg) {
      int row = mf * 16 + grp * 4 + rg;
      float ss = red[0][row][0] + red[1][row][0];
      float qq = red[0][row][1] + red[1][row][1];
      float mu = ss * (1.f / CH);
      float var = fmaxf(qq * (1.f / CH) - mu * mu, 0.f);
      float rs = rsqrtf(var + 1e-5f);
      #pragma unroll
      for (int nf = 0; nf < NF; ++nf) {
        float v = (acc1[mf][nf][rg] - mu) * rs * gr[nf] + ber[nf];
        hb[row][ni * (CH / 2) + nf * 16 + lrow] = f2bf(fmaxf(v, 0.f));
      }
    }
  __syncthreads();   // barrier 2: full hb ready

  // ---- GEMM2: wave ni computes out cols [ni*64, ni*64+64) ----
  float b2r[4];
  #pragma unroll
  for (int nf2 = 0; nf2 < 4; ++nf2) b2r[nf2] = b2[ni * 64 + nf2 * 16 + lrow];

  f32x4 acc2[2][4];
  #pragma unroll
  for (int mf = 0; mf < 2; ++mf)
    #pragma unroll
    for (int nf2 = 0; nf2 < 4; ++nf2) acc2[mf][nf2] = 0;
  const unsigned short* wbl2 = w2f + (size_t)lane * 8;
  bfrag8 cr[2][4];
  #pragma unroll
  for (int nf2 = 0; nf2 < 4; ++nf2)
    cr[0][nf2] = *(const bfrag8*)(wbl2 + ((size_t)(ni * 4 + nf2) * KS2) * 512);
  #pragma unroll
  for (int k2 = 0; k2 < KS2; ++k2) {
    if (k2 + 1 < KS2) {
      #pragma unroll
      for (int nf2 = 0; nf2 < 4; ++nf2)
        cr[(k2 + 1) & 1][nf2] = *(const bfrag8*)(wbl2 + ((size_t)(ni * 4 + nf2) * KS2 + k2 + 1) * 512);
    }
    bfrag8 a0 = *(const bfrag8*)&hb[lrow][k2 * 32 + kq];
    bfrag8 a1 = *(const bfrag8*)&hb[16 + lrow][k2 * 32 + kq];
    #pragma unroll
    for (int nf2 = 0; nf2 < 4; ++nf2) {
      acc2[0][nf2] = __builtin_amdgcn_mfma_f32_16x16x32_bf16(a0, cr[k2 & 1][nf2], acc2[0][nf2], 0, 0, 0);
      acc2[1][nf2] = __builtin_amdgcn_mfma_f32_16x16x32_bf16(a1, cr[k2 & 1][nf2], acc2[1][nf2], 0, 0, 0);
    }
  }

  // ---- stores (eid via wave shuffle) ----
  #pragma unroll
  for (int mf = 0; mf < 2; ++mf)
    #pragma unroll
    for (int rg = 0; rg < 4; ++rg) {
      const int rowLow = grp * 4 + rg;
      const int eid = __shfl(mf ? qb.z : qa.z, rowLow);
      if (base + mf * 16 + rowLow < c) {
        float* po = out + (size_t)eid * 128 + ni * 64 + lrow;
        #pragma unroll
        for (int nf2 = 0; nf2 < 4; ++nf2)
          po[nf2 * 16] = acc2[mf][nf2][rg] + b2r[nf2];
      }
    }
}

struct Args {
  const float *h_nodes, *edge_scalars;
  const float *emb_et, *emb_ct, *emb_pr;
  const unsigned short *w1c, *w2c;
  const float *cb1, *cg, *cbe, *cb2;
  const unsigned short *w1n, *w2n;
  const float *nb1, *ng, *nbe, *nb2;
  const int *cnt;
  const int4 *r0, *r1;
  float* out;
};

__global__ __launch_bounds__(128, 2) void edge_mlp_all(Args A) {
  __shared__ alignas(16) char smraw[13312 + 512];
  const int lane = threadIdx.x & 63;
  const int ni   = threadIdx.x >> 6;
  const int b = blockIdx.x;
  const int c0 = A.cnt[0];
  const int t0 = (c0 + 31) >> 5;
  if (b < t0) {
    mlp_tile2<192>(smraw, lane, ni, b, c0, 0, A.r0, A.h_nodes, A.edge_scalars,
                   A.emb_et, A.emb_ct, A.emb_pr, A.w1c, A.w2c,
                   A.cb1, A.cg, A.cbe, A.cb2, A.out);
  } else {
    const int c1 = A.cnt[1];
    const int t2 = b - t0;
    if (t2 * 32 < c1)
      mlp_tile2<128>(smraw, lane, ni, t2, c1, 1, A.r1, A.h_nodes, A.edge_scalars,
                     A.emb_et, A.emb_ct, A.emb_pr, A.w1n, A.w2n,
                     A.nb1, A.ng, A.nbe, A.nb2, A.out);
  }
}

extern "C" void kernel_launch(void* const* d_in, const int* in_sizes, int n_in,
                              void* d_out, int out_size, void* d_ws, size_t ws_size,
                              hipStream_t stream) {
  (void)n_in; (void)out_size; (void)ws_size;
  const float* h_nodes      = (const float*)d_in[0];
  const float* edge_scalars = (const float*)d_in[1];
  const int*   edge_src     = (const int*)d_in[2];
  const int*   edge_dst     = (const int*)d_in[3];
  const int*   edge_type    = (const int*)d_in[4];
  const int*   ct_s         = (const int*)d_in[5];
  const int*   ct_d         = (const int*)d_in[6];
  const int*   pr_s         = (const int*)d_in[7];
  const int*   pr_d         = (const int*)d_in[8];
  const float* emb_et       = (const float*)d_in[9];
  const float* emb_ct       = (const float*)d_in[10];
  const float* emb_pr       = (const float*)d_in[11];
  const float* cW1 = (const float*)d_in[12];
  const float* cb1 = (const float*)d_in[13];
  const float* cg  = (const float*)d_in[14];
  const float* cbe = (const float*)d_in[15];
  const float* cW2 = (const float*)d_in[16];
  const float* cb2 = (const float*)d_in[17];
  const float* nW1 = (const float*)d_in[18];
  const float* nb1 = (const float*)d_in[19];
  const float* ng  = (const float*)d_in[20];
  const float* nbe = (const float*)d_in[21];
  const float* nW2 = (const float*)d_in[22];
  const float* nb2 = (const float*)d_in[23];
  const int n_edges = in_sizes[2];
  float* out = (float*)d_out;

  char* ws = (char*)d_ws;
  int* cnt = (int*)ws;
  int4* r0 = (int4*)(ws + 256);
  int4* r1 = r0 + n_edges;
  size_t woff = (256 + (size_t)2 * n_edges * sizeof(int4) + 255) & ~(size_t)255;
  unsigned short* w1c = (unsigned short*)(ws + woff);
  unsigned short* w1n = w1c + 12 * KS * 512;
  unsigned short* w2c = w1n + 8 * KS * 512;
  unsigned short* w2n = w2c + 8 * 6 * 512;

  prep_weights<<<1080, 256, 0, stream>>>(cW1, nW1, cW2, nW2, w1c, w1n, w2c, w2n, cnt);
  compact_edges<<<(n_edges + 255) / 256, 256, 0, stream>>>(edge_type, edge_src, edge_dst,
                                                           ct_s, ct_d, pr_s, pr_d,
                                                           cnt, r0, r1, out, n_edges);

  Args A;
  A.h_nodes = h_nodes; A.edge_scalars = edge_scalars;
  A.emb_et = emb_et; A.emb_ct = emb_ct; A.emb_pr = emb_pr;
  A.w1c = w1c; A.w2c = w2c; A.cb1 = cb1; A.cg = cg; A.cbe = cbe; A.cb2 = cb2;
  A.w1n = w1n; A.w2n = w2n; A.nb1 = nb1; A.ng = ng; A.nbe = nbe; A.nb2 = nb2;
  A.cnt = cnt; A.r0 = r0; A.r1 = r1; A.out = out;

  const int tiles = (n_edges + 31) / 32 + 2;
  edge_mlp_all<<<tiles, 128, 0, stream>>>(A);
}

// Round 11
// 243.142 us; speedup vs baseline: 1.2278x; 1.0673x over previous
//
#include <hip/hip_runtime.h>

#define KS 23        // 736/32 K-steps for GEMM1
#define RING 3       // LDS B-ring slots per wave

typedef short bfrag8 __attribute__((ext_vector_type(8)));
typedef float f32x4 __attribute__((ext_vector_type(4)));

__device__ __forceinline__ unsigned short f2bf(float f) {
  union { float f; unsigned u; } v; v.f = f;
  unsigned r = v.u + 0x7fffu + ((v.u >> 16) & 1u);
  return (unsigned short)(r >> 16);
}
__device__ __forceinline__ unsigned pk2(float a, float b) {
  return (unsigned)f2bf(a) | ((unsigned)f2bf(b) << 16);
}
__device__ __forceinline__ float bf2f(short s) {
  union { unsigned u; float f; } v;
  v.u = ((unsigned)(unsigned short)s) << 16;
  return v.f;
}
__device__ __forceinline__ void gload_lds16(const void* g, void* l) {
  __builtin_amdgcn_global_load_lds(
      (const __attribute__((address_space(1))) void*)g,
      (__attribute__((address_space(3))) void*)l, 16, 0, 0);
}

// ---- prep: weights -> fragment-major bf16 (contiguous 1KB per n16 x k32 MFMA tile) ----
__global__ void prep_weights(const float* __restrict__ cW1, const float* __restrict__ nW1,
                             const float* __restrict__ cW2, const float* __restrict__ nW2,
                             unsigned short* __restrict__ w1c, unsigned short* __restrict__ w1n,
                             unsigned short* __restrict__ w2c, unsigned short* __restrict__ w2n,
                             int* __restrict__ cnt) {
  int i = blockIdx.x * blockDim.x + threadIdx.x;
  if (i == 0) { cnt[0] = 0; cnt[1] = 0; }
  const int T0 = 12 * KS * 512, T1 = 8 * KS * 512, T2 = 8 * 6 * 512, T3 = 8 * 4 * 512;
  const int tot = T0 + T1 + T2 + T3;
  for (; i < tot; i += gridDim.x * blockDim.x) {
    int idx = i;
    const float* src; unsigned short* dst; int N, Kreal, KSm, rel;
    if (idx < T0)              { src = cW1; dst = w1c; N = 192; Kreal = 726; KSm = KS; rel = idx; }
    else if ((idx -= T0) < T1) { src = nW1; dst = w1n; N = 128; Kreal = 726; KSm = KS; rel = idx; }
    else if ((idx -= T1) < T2) { src = cW2; dst = w2c; N = 128; Kreal = 192; KSm = 6;  rel = idx; }
    else { idx -= T2;            src = nW2; dst = w2n; N = 128; Kreal = 128; KSm = 4;  rel = idx; }
    int blk = rel >> 9, within = rel & 511;
    int l = within >> 3, e = within & 7;
    int n16 = blk / KSm, k32 = blk - n16 * KSm;
    int n = n16 * 16 + (l & 15);
    int k = k32 * 32 + ((l >> 4) * 8) + e;
    dst[rel] = f2bf(k < Kreal ? src[(size_t)k * N + n] : 0.f);
  }
}

// ---- compaction: per-type packed records {src, dst, eid, packed_indices} ----
__global__ void compact_edges(const int* __restrict__ et,
                              const int* __restrict__ esrc, const int* __restrict__ edst,
                              const int* __restrict__ cts, const int* __restrict__ ctd,
                              const int* __restrict__ prs, const int* __restrict__ prd,
                              int* __restrict__ cnt, int4* __restrict__ r0, int4* __restrict__ r1,
                              float* __restrict__ out, int n) {
  int i = blockIdx.x * blockDim.x + threadIdx.x;
  for (; i < n; i += gridDim.x * blockDim.x) {
    int ty = et[i];
    if (ty == 0 || ty == 1) {
      int c1 = cts[i]; c1 = ((unsigned)c1 < 256u) ? c1 : 0;
      int c2 = ctd[i]; c2 = ((unsigned)c2 < 256u) ? c2 : 0;
      int p1 = prs[i]; p1 = ((unsigned)p1 < 64u)  ? p1 : 0;
      int p2 = prd[i]; p2 = ((unsigned)p2 < 64u)  ? p2 : 0;
      int4 rec; rec.x = esrc[i]; rec.y = edst[i]; rec.z = i;
      rec.w = c1 | (c2 << 8) | (p1 << 16) | (p2 << 22);
      if (ty == 0) r0[atomicAdd(&cnt[0], 1)] = rec;
      else         r1[atomicAdd(&cnt[1], 1)] = rec;
    } else {
      float4 z = make_float4(0.f, 0.f, 0.f, 0.f);
      float4* po = (float4*)(out + (size_t)i * 128);
      #pragma unroll
      for (int j = 0; j < 32; ++j) po[j] = z;
    }
  }
}

__device__ __forceinline__ void loadrow(const float* __restrict__ p, int kq, bfrag8 f[4]) {
  #pragma unroll
  for (int j = 0; j < 4; ++j) {
    float4 x = *(const float4*)(p + j * 32 + kq);
    float4 y = *(const float4*)(p + j * 32 + kq + 4);
    union { bfrag8 b; uint4 q; } r;
    r.q = make_uint4(pk2(x.x, x.y), pk2(x.z, x.w), pk2(y.x, y.y), pk2(y.z, y.w));
    f[j] = r.b;
  }
}

__device__ __forceinline__ bfrag8 dfrag(bfrag8 u, bfrag8 v, int op) {
  unsigned w[4];
  #pragma unroll
  for (int i = 0; i < 4; ++i) {
    float u0 = bf2f(u[2 * i]),     v0 = bf2f(v[2 * i]);
    float u1 = bf2f(u[2 * i + 1]), v1 = bf2f(v[2 * i + 1]);
    float x0 = (op == 0) ? u0 * v0 : (op == 1) ? fabsf(u0 - v0) : v0 - u0;
    float x1 = (op == 0) ? u1 * v1 : (op == 1) ? fabsf(u1 - v1) : v1 - u1;
    w[i] = pk2(x0, x1);
  }
  union { bfrag8 b; uint4 q; } r;
  r.q = make_uint4(w[0], w[1], w[2], w[3]);
  return r.b;
}

// ---- 2 waves on 32 edges; wave ni owns N-half; B staged via wave-private async LDS ring ----
template <int CH>
__device__ __forceinline__ void mlp_tile2(
    char* smraw, int lane, int ni, int tile, int c, int etv,
    const int4* __restrict__ rec,
    const float* __restrict__ h_nodes, const float* __restrict__ edge_scalars,
    const float* __restrict__ emb_et, const float* __restrict__ emb_ct, const float* __restrict__ emb_pr,
    const unsigned short* __restrict__ w1f, const unsigned short* __restrict__ w2f,
    const float* __restrict__ b1, const float* __restrict__ g,
    const float* __restrict__ beta, const float* __restrict__ b2,
    float* __restrict__ out)
{
  constexpr int NF  = CH / 32;        // GEMM1 n-frags per wave (6 or 4)
  constexpr int KS2 = CH / 32;        // GEMM2 K-steps
  constexpr int HST = CH + 8;
  constexpr int EST = 104;
  constexpr int RB  = RING * NF * 1024;   // ring bytes per wave
  unsigned short* ring = (unsigned short*)(smraw + ni * RB);
  unsigned short (*emb)[EST] = (unsigned short (*)[EST])(smraw + 2 * RB + ni * 6656);
  unsigned short (*hb)[HST]  = (unsigned short (*)[HST])smraw;           // overlays rings post-barrier1
  float (*red)[32][2] = (float (*)[32][2])(smraw + 2 * RB + 13312);

  const int lrow = lane & 15;
  const int grp  = lane >> 4;
  const int kq   = grp * 8;
  const int base = tile * 32;

  int4 qa = rec[min(base + lrow, c - 1)];
  int4 qb = rec[min(base + 16 + lrow, c - 1)];

  // ---- emb gather into wave-private LDS (2 lanes per row) ----
  {
    const int rr = lane >> 1, hf = lane & 1;
    int4 qe = rec[min(base + rr, c - 1)];
    const int pk = qe.w;
    if (hf == 0) {
      const float* tps[3] = { emb_et + etv * 16,
                              emb_ct + (pk & 255) * 16,
                              emb_ct + ((pk >> 8) & 255) * 16 };
      #pragma unroll
      for (int tb = 0; tb < 3; ++tb) {
        const float4* tp = (const float4*)tps[tb];
        float4 a = tp[0], b4 = tp[1], c4 = tp[2], d4 = tp[3];
        *(uint4*)&emb[rr][tb * 16 + 0] =
          make_uint4(pk2(a.x, a.y), pk2(a.z, a.w), pk2(b4.x, b4.y), pk2(b4.z, b4.w));
        *(uint4*)&emb[rr][tb * 16 + 8] =
          make_uint4(pk2(c4.x, c4.y), pk2(c4.z, c4.w), pk2(d4.x, d4.y), pk2(d4.z, d4.w));
      }
    } else {
      const float* tps[2] = { emb_pr + ((pk >> 16) & 63) * 16,
                              emb_pr + ((pk >> 22) & 63) * 16 };
      #pragma unroll
      for (int tb = 0; tb < 2; ++tb) {
        const float4* tp = (const float4*)tps[tb];
        float4 a = tp[0], b4 = tp[1], c4 = tp[2], d4 = tp[3];
        *(uint4*)&emb[rr][48 + tb * 16 + 0] =
          make_uint4(pk2(a.x, a.y), pk2(a.z, a.w), pk2(b4.x, b4.y), pk2(b4.z, b4.w));
        *(uint4*)&emb[rr][48 + tb * 16 + 8] =
          make_uint4(pk2(c4.x, c4.y), pk2(c4.z, c4.w), pk2(d4.x, d4.y), pk2(d4.z, d4.w));
      }
      const float2* sp = (const float2*)(edge_scalars + (size_t)qe.z * 6);
      float2 s0 = sp[0], s1 = sp[1], s2 = sp[2];
      float v0 = fminf(fmaxf(s0.x, -10.f), 10.f), v1 = fminf(fmaxf(s0.y, -10.f), 10.f);
      float v2 = fminf(fmaxf(s1.x, -10.f), 10.f), v3 = fminf(fmaxf(s1.y, -10.f), 10.f);
      float v4 = fminf(fmaxf(s2.x, -10.f), 10.f), v5 = fminf(fmaxf(s2.y, -10.f), 10.f);
      *(uint4*)&emb[rr][80] = make_uint4(pk2(v0, v1), pk2(v2, v3), pk2(v4, v5), 0u);
      *(uint4*)&emb[rr][88] = make_uint4(0u, 0u, 0u, 0u);
    }
  }

  // ---- u,v A-fragments straight into registers ----
  bfrag8 ua[4], va[4], ub[4], vb[4];
  loadrow(h_nodes + (size_t)qa.x * 128, kq, ua);
  loadrow(h_nodes + (size_t)qa.y * 128, kq, va);
  loadrow(h_nodes + (size_t)qb.x * 128, kq, ub);
  loadrow(h_nodes + (size_t)qb.y * 128, kq, vb);

  // ---- async B staging: slab kk -> ring slot kk%RING (NF x 1KB tiles, 1 instr each) ----
  auto stage = [&](int kk) {
    const int slot = kk % RING;
    #pragma unroll
    for (int nf = 0; nf < NF; ++nf) {
      const unsigned short* gp = w1f + (((size_t)(ni * NF + nf)) * KS + kk) * 512 + lane * 8;
      unsigned short* lp = ring + (slot * NF + nf) * 512;
      gload_lds16(gp, lp);
    }
  };
  stage(0); stage(1); stage(2);   // prologue: 3 slabs in flight

  f32x4 acc1[2][NF];
  #pragma unroll
  for (int mf = 0; mf < 2; ++mf)
    #pragma unroll
    for (int nf = 0; nf < NF; ++nf) acc1[mf][nf] = 0;

  #pragma unroll
  for (int kk = 0; kk < 23; ++kk) {
    // wait: slab kk resident (counted, never full drain until tail)
    if (kk < 21) {
      if constexpr (NF == 6) asm volatile("s_waitcnt vmcnt(12)" ::: "memory");
      else                   asm volatile("s_waitcnt vmcnt(8)"  ::: "memory");
    } else if (kk == 21) {
      if constexpr (NF == 6) asm volatile("s_waitcnt vmcnt(6)" ::: "memory");
      else                   asm volatile("s_waitcnt vmcnt(4)" ::: "memory");
    } else {
      asm volatile("s_waitcnt vmcnt(0)" ::: "memory");
    }
    bfrag8 a0, a1;
    const int seg = kk >> 2, k = kk & 3;
    if (kk >= 20) {
      a0 = *(const bfrag8*)&emb[lrow][(kk - 20) * 32 + kq];
      a1 = *(const bfrag8*)&emb[16 + lrow][(kk - 20) * 32 + kq];
    } else if (seg == 0) { a0 = ua[k]; a1 = ub[k]; }
    else if (seg == 1)   { a0 = va[k]; a1 = vb[k]; }
    else { a0 = dfrag(ua[k], va[k], seg - 2); a1 = dfrag(ub[k], vb[k], seg - 2); }
    const int slot = kk % RING;
    #pragma unroll
    for (int nf = 0; nf < NF; ++nf) {
      bfrag8 bf = *(const bfrag8*)(ring + (slot * NF + nf) * 512 + lane * 8);
      acc1[0][nf] = __builtin_amdgcn_mfma_f32_16x16x32_bf16(a0, bf, acc1[0][nf], 0, 0, 0);
      acc1[1][nf] = __builtin_amdgcn_mfma_f32_16x16x32_bf16(a1, bf, acc1[1][nf], 0, 0, 0);
    }
    // all ds_reads of this slot done before its slot is re-staged
    if (kk + RING < 23) {
      asm volatile("s_waitcnt lgkmcnt(0)" ::: "memory");
      stage(kk + RING);
    }
  }

  // ---- bias fold + partial LN sums over this wave's half ----
  float b1r[NF], gr[NF], ber[NF];
  #pragma unroll
  for (int nf = 0; nf < NF; ++nf) {
    int n = ni * (CH / 2) + nf * 16 + lrow;
    b1r[nf] = b1[n]; gr[nf] = g[n]; ber[nf] = beta[n];
  }
  float sums[2][4], sqs[2][4];
  #pragma unroll
  for (int mf = 0; mf < 2; ++mf)
    #pragma unroll
    for (int rg = 0; rg < 4; ++rg) {
      float s = 0.f, qd = 0.f;
      #pragma unroll
      for (int nf = 0; nf < NF; ++nf) {
        float v = acc1[mf][nf][rg] + b1r[nf];
        acc1[mf][nf][rg] = v;
        s += v; qd += v * v;
      }
      sums[mf][rg] = s; sqs[mf][rg] = qd;
    }
  #pragma unroll
  for (int d = 1; d < 16; d <<= 1) {
    #pragma unroll
    for (int mf = 0; mf < 2; ++mf)
      #pragma unroll
      for (int rg = 0; rg < 4; ++rg) {
        sums[mf][rg] += __shfl_xor(sums[mf][rg], d);
        sqs[mf][rg]  += __shfl_xor(sqs[mf][rg], d);
      }
  }
  if (lrow == 0) {
    #pragma unroll
    for (int mf = 0; mf < 2; ++mf)
      #pragma unroll
      for (int rg = 0; rg < 4; ++rg) {
        int row = mf * 16 + grp * 4 + rg;
        red[ni][row][0] = sums[mf][rg];
        red[ni][row][1] = sqs[mf][rg];
      }
  }
  __syncthreads();   // barrier 1: partials ready; rings dead -> hb overlay safe

  #pragma unroll
  for (int mf = 0; mf < 2; ++mf)
    #pragma unroll
    for (int rg = 0; rg < 4; ++rg) {
      int row = mf * 16 + grp * 4 + rg;
      float ss = red[0][row][0] + red[1][row][0];
      float qq = red[0][row][1] + red[1][row][1];
      float mu = ss * (1.f / CH);
      float var = fmaxf(qq * (1.f / CH) - mu * mu, 0.f);
      float rs = rsqrtf(var + 1e-5f);
      #pragma unroll
      for (int nf = 0; nf < NF; ++nf) {
        float v = (acc1[mf][nf][rg] - mu) * rs * gr[nf] + ber[nf];
        hb[row][ni * (CH / 2) + nf * 16 + lrow] = f2bf(fmaxf(v, 0.f));
      }
    }
  __syncthreads();   // barrier 2: full hb ready

  // ---- GEMM2: wave ni computes out cols [ni*64, ni*64+64) ----
  float b2r[4];
  #pragma unroll
  for (int nf2 = 0; nf2 < 4; ++nf2) b2r[nf2] = b2[ni * 64 + nf2 * 16 + lrow];

  f32x4 acc2[2][4];
  #pragma unroll
  for (int mf = 0; mf < 2; ++mf)
    #pragma unroll
    for (int nf2 = 0; nf2 < 4; ++nf2) acc2[mf][nf2] = 0;
  const unsigned short* wbl2 = w2f + (size_t)lane * 8;
  bfrag8 cr[2][4];
  #pragma unroll
  for (int nf2 = 0; nf2 < 4; ++nf2)
    cr[0][nf2] = *(const bfrag8*)(wbl2 + ((size_t)(ni * 4 + nf2) * KS2) * 512);
  #pragma unroll
  for (int k2 = 0; k2 < KS2; ++k2) {
    if (k2 + 1 < KS2) {
      #pragma unroll
      for (int nf2 = 0; nf2 < 4; ++nf2)
        cr[(k2 + 1) & 1][nf2] = *(const bfrag8*)(wbl2 + ((size_t)(ni * 4 + nf2) * KS2 + k2 + 1) * 512);
    }
    bfrag8 a0 = *(const bfrag8*)&hb[lrow][k2 * 32 + kq];
    bfrag8 a1 = *(const bfrag8*)&hb[16 + lrow][k2 * 32 + kq];
    #pragma unroll
    for (int nf2 = 0; nf2 < 4; ++nf2) {
      acc2[0][nf2] = __builtin_amdgcn_mfma_f32_16x16x32_bf16(a0, cr[k2 & 1][nf2], acc2[0][nf2], 0, 0, 0);
      acc2[1][nf2] = __builtin_amdgcn_mfma_f32_16x16x32_bf16(a1, cr[k2 & 1][nf2], acc2[1][nf2], 0, 0, 0);
    }
  }

  // ---- stores (eid via wave shuffle) ----
  #pragma unroll
  for (int mf = 0; mf < 2; ++mf)
    #pragma unroll
    for (int rg = 0; rg < 4; ++rg) {
      const int rowLow = grp * 4 + rg;
      const int eid = __shfl(mf ? qb.z : qa.z, rowLow);
      if (base + mf * 16 + rowLow < c) {
        float* po = out + (size_t)eid * 128 + ni * 64 + lrow;
        #pragma unroll
        for (int nf2 = 0; nf2 < 4; ++nf2)
          po[nf2 * 16] = acc2[mf][nf2][rg] + b2r[nf2];
      }
    }
}

struct Args {
  const float *h_nodes, *edge_scalars;
  const float *emb_et, *emb_ct, *emb_pr;
  const unsigned short *w1c, *w2c;
  const float *cb1, *cg, *cbe, *cb2;
  const unsigned short *w1n, *w2n;
  const float *nb1, *ng, *nbe, *nb2;
  const int *cnt;
  const int4 *r0, *r1;
  float* out;
};

__global__ __launch_bounds__(128, 2) void edge_mlp_all(Args A) {
  // max layout (CH=192): 2 rings 36864 + emb 13312 + red 512 = 50688
  __shared__ alignas(16) char smraw[50688];
  const int lane = threadIdx.x & 63;
  const int ni   = threadIdx.x >> 6;
  const int b = blockIdx.x;
  const int c0 = A.cnt[0];
  const int t0 = (c0 + 31) >> 5;
  if (b < t0) {
    mlp_tile2<192>(smraw, lane, ni, b, c0, 0, A.r0, A.h_nodes, A.edge_scalars,
                   A.emb_et, A.emb_ct, A.emb_pr, A.w1c, A.w2c,
                   A.cb1, A.cg, A.cbe, A.cb2, A.out);
  } else {
    const int c1 = A.cnt[1];
    const int t2 = b - t0;
    if (t2 * 32 < c1)
      mlp_tile2<128>(smraw, lane, ni, t2, c1, 1, A.r1, A.h_nodes, A.edge_scalars,
                     A.emb_et, A.emb_ct, A.emb_pr, A.w1n, A.w2n,
                     A.nb1, A.ng, A.nbe, A.nb2, A.out);
  }
}

extern "C" void kernel_launch(void* const* d_in, const int* in_sizes, int n_in,
                              void* d_out, int out_size, void* d_ws, size_t ws_size,
                              hipStream_t stream) {
  (void)n_in; (void)out_size; (void)ws_size;
  const float* h_nodes      = (const float*)d_in[0];
  const float* edge_scalars = (const float*)d_in[1];
  const int*   edge_src     = (const int*)d_in[2];
  const int*   edge_dst     = (const int*)d_in[3];
  const int*   edge_type    = (const int*)d_in[4];
  const int*   ct_s         = (const int*)d_in[5];
  const int*   ct_d         = (const int*)d_in[6];
  const int*   pr_s         = (const int*)d_in[7];
  const int*   pr_d         = (const int*)d_in[8];
  const float* emb_et       = (const float*)d_in[9];
  const float* emb_ct       = (const float*)d_in[10];
  const float* emb_pr       = (const float*)d_in[11];
  const float* cW1 = (const float*)d_in[12];
  const float* cb1 = (const float*)d_in[13];
  const float* cg  = (const float*)d_in[14];
  const float* cbe = (const float*)d_in[15];
  const float* cW2 = (const float*)d_in[16];
  const float* cb2 = (const float*)d_in[17];
  const float* nW1 = (const float*)d_in[18];
  const float* nb1 = (const float*)d_in[19];
  const float* ng  = (const float*)d_in[20];
  const float* nbe = (const float*)d_in[21];
  const float* nW2 = (const float*)d_in[22];
  const float* nb2 = (const float*)d_in[23];
  const int n_edges = in_sizes[2];
  float* out = (float*)d_out;

  char* ws = (char*)d_ws;
  int* cnt = (int*)ws;
  int4* r0 = (int4*)(ws + 256);
  int4* r1 = r0 + n_edges;
  size_t woff = (256 + (size_t)2 * n_edges * sizeof(int4) + 255) & ~(size_t)255;
  unsigned short* w1c = (unsigned short*)(ws + woff);
  unsigned short* w1n = w1c + 12 * KS * 512;
  unsigned short* w2c = w1n + 8 * KS * 512;
  unsigned short* w2n = w2c + 8 * 6 * 512;

  prep_weights<<<1080, 256, 0, stream>>>(cW1, nW1, cW2, nW2, w1c, w1n, w2c, w2n, cnt);
  compact_edges<<<(n_edges + 255) / 256, 256, 0, stream>>>(edge_type, edge_src, edge_dst,
                                                           ct_s, ct_d, pr_s, pr_d,
                                                           cnt, r0, r1, out, n_edges);

  Args A;
  A.h_nodes = h_nodes; A.edge_scalars = edge_scalars;
  A.emb_et = emb_et; A.emb_ct = emb_ct; A.emb_pr = emb_pr;
  A.w1c = w1c; A.w2c = w2c; A.cb1 = cb1; A.cg = cg; A.cbe = cbe; A.cb2 = cb2;
  A.w1n = w1n; A.w2n = w2n; A.nb1 = nb1; A.ng = ng; A.nbe = nbe; A.nb2 = nb2;
  A.cnt = cnt; A.r0 = r0; A.r1 = r1; A.out = out;

  const int tiles = (n_edges + 31) / 32 + 2;
  edge_mlp_all<<<tiles, 128, 0, stream>>>(A);
}